// Round 1
// 402.676 us; speedup vs baseline: 1.0435x; 1.0435x over previous
//
#include <hip/hip_runtime.h>
#include <hip/hip_bf16.h>

// Problem constants (match reference setup_inputs)
#define BATCH 8192
#define HID   512
#define DEPTH 16

// One WAVE per sample: 2048 blocks x 256 threads (4 waves). Each lane holds
// 8 floats of the hidden row in registers. Weight rows stream through a
// depth-4 rolling prefetch (8 float4 loads in flight per wave).
//
// KEY CHANGE vs previous version: rows d >= L are masked out of the BCE by
// the reference, so their weight rows never influence the result. We now
// skip loading/computing them entirely: rows 0..7 are unconditional
// (lengths are drawn from [8, 16]), rows 8..15 are guarded by wave-uniform
// scalar branches on L. This cuts the dominant weight-gather stream by
// (16-L)/16 -- 25% on average -- and is bitwise identical to before.
//
// Reduction scheme (unchanged):
//   per node d: 2 xor steps (masks 32,16) -> lane l holds coset partial
//   S_d[l&15]; quadrant q=l>>4 captures node d=4t+q into slot y[t];
//   4 batched xor reductions (masks 1,2,4,8) then finish 4 nodes at once:
//   y[t] = logit_{4t+q} replicated across quadrant q. Masks 1,2,4,8 never
//   cross quadrant boundaries (bits 4-5), so the y[t]=0 slots of masked
//   nodes stay isolated from live quadrants.
__global__ __launch_bounds__(256) void hsm_main_kernel(
    const float* __restrict__ hidden,       // [B, H]
    const int*   __restrict__ target,       // [B]
    const float* __restrict__ weights,      // [V, D, H]
    const float* __restrict__ codes,        // [V, D]
    const int*   __restrict__ lengths,      // [V]
    float*       __restrict__ partial)      // [gridDim.x]
{
    __shared__ float sblk[4];

    const int tid  = threadIdx.x;
    const int wave = tid >> 6;
    const int lane = tid & 63;
    const int q    = lane >> 4;             // quadrant 0..3
    const int b    = blockIdx.x * 4 + wave;

    int w = target[b];                      // wave-uniform
    w = __builtin_amdgcn_readfirstlane(w);  // force scalar for addressing
    int L = lengths[w];
    L = __builtin_amdgcn_readfirstlane(L);  // wave-uniform path length, 8..16

    // Hidden row in registers: 512 floats = 128 float4; lane holds [l], [l+64].
    const float4* hrow = (const float4*)(hidden + (size_t)b * HID);
    const float4 h0 = hrow[lane];
    const float4 h1 = hrow[lane + 64];

    const float4* wbase = (const float4*)(weights + (size_t)w * (DEPTH * HID));

    // Rolling prefetch, depth 4 rows (each row: 2 float4 per lane).
    // L >= 8 guaranteed, so rows 0..3 always exist.
    float4 wa[4], wb[4];
#pragma unroll
    for (int i = 0; i < 4; ++i) {
        const float4* wr = wbase + i * (HID / 4);
        wa[i] = wr[lane];
        wb[i] = wr[lane + 64];
    }

    // y slots init to 0: masked nodes (d >= L) contribute exact zeros to the
    // batched reduce and are skipped by the BCE mask anyway.
    float y[4];
    y[0] = 0.0f; y[1] = 0.0f; y[2] = 0.0f; y[3] = 0.0f;

    // Body for row d. d must be a literal so y[(d)>>2] stays a static
    // register index (runtime-indexed register arrays go to scratch).
#define HSM_BODY(d)                                                    \
    {                                                                  \
        const int slot = (d) & 3;                                      \
        const float4 w0 = wa[slot];                                    \
        const float4 w1 = wb[slot];                                    \
        if ((d) + 4 < L) {            /* prefetch row d+4 into slot */ \
            const float4* wr = wbase + ((d) + 4) * (HID / 4);          \
            wa[slot] = wr[lane];                                       \
            wb[slot] = wr[lane + 64];                                  \
        }                                                              \
        float acc;                                                     \
        acc = w0.x * h0.x;                                             \
        acc = fmaf(w0.y, h0.y, acc);                                   \
        acc = fmaf(w0.z, h0.z, acc);                                   \
        acc = fmaf(w0.w, h0.w, acc);                                   \
        acc = fmaf(w1.x, h1.x, acc);                                   \
        acc = fmaf(w1.y, h1.y, acc);                                   \
        acc = fmaf(w1.z, h1.z, acc);                                   \
        acc = fmaf(w1.w, h1.w, acc);                                   \
        /* 2-step coset reduce: lane l -> sum over {l, l^16, l^32, l^48} */ \
        acc += __shfl_xor(acc, 32, 64);                                \
        acc += __shfl_xor(acc, 16, 64);                                \
        if (q == ((d) & 3)) y[(d) >> 2] = acc;                         \
    }

    // Rows 0..7: always on the path (L >= 8).
    HSM_BODY(0) HSM_BODY(1) HSM_BODY(2) HSM_BODY(3)
    HSM_BODY(4) HSM_BODY(5) HSM_BODY(6) HSM_BODY(7)

    // Rows 8..15: wave-uniform scalar guards; nested so a short path takes
    // one branch out.
    if (L > 8)  { HSM_BODY(8)
    if (L > 9)  { HSM_BODY(9)
    if (L > 10) { HSM_BODY(10)
    if (L > 11) { HSM_BODY(11)
    if (L > 12) { HSM_BODY(12)
    if (L > 13) { HSM_BODY(13)
    if (L > 14) { HSM_BODY(14)
    if (L > 15) { HSM_BODY(15) } } } } } } } }

#undef HSM_BODY

    // Batched finish: sum the 16 coset partials (over lane&15) for 4 nodes at
    // once. After this, y[t] = logit_{4t+q}, replicated within quadrant q.
#pragma unroll
    for (int t = 0; t < 4; ++t) {
        y[t] += __shfl_xor(y[t], 1, 64);
        y[t] += __shfl_xor(y[t], 2, 64);
        y[t] += __shfl_xor(y[t], 4, 64);
        y[t] += __shfl_xor(y[t], 8, 64);
    }

    // BCE terms for nodes {q, q+4, q+8, q+12}; masked by path length.
    const float* crow = codes + (size_t)w * DEPTH;
    float s = 0.0f;
#pragma unroll
    for (int t = 0; t < 4; ++t) {
        const int d = 4 * t + q;
        if (d < L) {
            const float x = y[t];
            const float tt = crow[d];
            // stable BCE-with-logits: max(x,0) - x*t + log1p(exp(-|x|))
            s += fmaxf(x, 0.0f) - x * tt + log1pf(__expf(-fabsf(x)));
        }
    }
    // Combine the 4 quadrants (each holds its own partial, replicated).
    s += __shfl_xor(s, 16, 64);
    s += __shfl_xor(s, 32, 64);

    if (lane == 0)
        sblk[wave] = s / ((float)L * (float)BATCH);
    __syncthreads();
    if (tid == 0)
        partial[blockIdx.x] = sblk[0] + sblk[1] + sblk[2] + sblk[3];
}

// Deterministic final reduction of the 2048 per-block partials (8 KB read).
// Unchanged (summation order preserved -> result stays bitwise identical).
__global__ __launch_bounds__(256) void hsm_reduce_kernel(
    const float* __restrict__ partial, float* __restrict__ out)
{
    __shared__ float sdata[256];
    float s = 0.0f;
    for (int i = threadIdx.x; i < BATCH / 4; i += 256) s += partial[i];
    sdata[threadIdx.x] = s;
    __syncthreads();
#pragma unroll
    for (int stride = 128; stride > 0; stride >>= 1) {
        if (threadIdx.x < stride)
            sdata[threadIdx.x] += sdata[threadIdx.x + stride];
        __syncthreads();
    }
    if (threadIdx.x == 0) out[0] = sdata[0];
}

extern "C" void kernel_launch(void* const* d_in, const int* in_sizes, int n_in,
                              void* d_out, int out_size, void* d_ws, size_t ws_size,
                              hipStream_t stream)
{
    const float* hidden  = (const float*)d_in[0];
    const int*   target  = (const int*)  d_in[1];
    const float* weights = (const float*)d_in[2];
    const float* codes   = (const float*)d_in[3];
    const int*   lengths = (const int*)  d_in[4];
    float* out = (float*)d_out;
    float* partial = (float*)d_ws;          // needs (BATCH/4)*4 = 8 KB of ws

    hsm_main_kernel<<<BATCH / 4, 256, 0, stream>>>(
        hidden, target, weights, codes, lengths, partial);
    hsm_reduce_kernel<<<1, 256, 0, stream>>>(partial, out);
}